// Round 4
// baseline (37.084 us; speedup 1.0000x reference)
//
#include <hip/hip_runtime.h>

// StructuredReadout: out[r, :] = node_states[idx[r], :]
// node_states: [N=1e6, D=256] f32 (1 GiB), idx: [R=1e5] int, out: [R, 256] f32.
//
// One 64-lane wave moves one 1 KiB row (16 B per lane), fully coalesced.
// 8-way independent unroll: 8 gather loads in flight per thread before any
// store. Index loads are hoisted to the SCALAR path: gid>>6 is wave-uniform,
// readfirstlane makes it provably uniform -> s_load_dword, so idx reads do
// not occupy VMEM (vmcnt) queue slots that the gathers need.
// Non-temporal stores: output written once, never re-read.

typedef float f32x4 __attribute__((ext_vector_type(4)));

__global__ __launch_bounds__(256) void StructuredReadout_47287589929655_kernel(
    const f32x4* __restrict__ src,    // node_states as [N, 64] f32x4
    const int* __restrict__ idx,      // readout indices [R]
    f32x4* __restrict__ dst,          // out as [R, 64] f32x4
    int total_f4)                     // R * 64
{
    const int S   = gridDim.x * blockDim.x;      // f32x4 stride per pass
    const int gid = blockIdx.x * blockDim.x + threadIdx.x;

    if (gid + 7 * S < total_f4) {
        const int c  = gid & 63;                                  // column
        const int w0 = __builtin_amdgcn_readfirstlane(gid >> 6);  // uniform row slot
        const int ws = S >> 6;                                    // row-slot stride

        // 8 scalar (SGPR-path) index loads, then 8 independent vector gathers.
        long long r0 = idx[w0 + 0 * ws];
        long long r1 = idx[w0 + 1 * ws];
        long long r2 = idx[w0 + 2 * ws];
        long long r3 = idx[w0 + 3 * ws];
        long long r4 = idx[w0 + 4 * ws];
        long long r5 = idx[w0 + 5 * ws];
        long long r6 = idx[w0 + 6 * ws];
        long long r7 = idx[w0 + 7 * ws];

        f32x4 v0 = src[r0 * 64 + c];
        f32x4 v1 = src[r1 * 64 + c];
        f32x4 v2 = src[r2 * 64 + c];
        f32x4 v3 = src[r3 * 64 + c];
        f32x4 v4 = src[r4 * 64 + c];
        f32x4 v5 = src[r5 * 64 + c];
        f32x4 v6 = src[r6 * 64 + c];
        f32x4 v7 = src[r7 * 64 + c];

        __builtin_nontemporal_store(v0, &dst[gid + 0 * S]);
        __builtin_nontemporal_store(v1, &dst[gid + 1 * S]);
        __builtin_nontemporal_store(v2, &dst[gid + 2 * S]);
        __builtin_nontemporal_store(v3, &dst[gid + 3 * S]);
        __builtin_nontemporal_store(v4, &dst[gid + 4 * S]);
        __builtin_nontemporal_store(v5, &dst[gid + 5 * S]);
        __builtin_nontemporal_store(v6, &dst[gid + 6 * S]);
        __builtin_nontemporal_store(v7, &dst[gid + 7 * S]);
    } else {
        for (int g = gid; g < total_f4; g += S) {
            long long r = idx[g >> 6];
            f32x4 v = src[r * 64 + (g & 63)];
            __builtin_nontemporal_store(v, &dst[g]);
        }
    }
}

extern "C" void kernel_launch(void* const* d_in, const int* in_sizes, int n_in,
                              void* d_out, int out_size, void* d_ws, size_t ws_size,
                              hipStream_t stream) {
    const f32x4* src = (const f32x4*)d_in[0];     // node_states [1e6 * 256] f32
    const int*   idx = (const int*)d_in[1];       // readout_indices [1e5]
    f32x4*       dst = (f32x4*)d_out;             // [1e5 * 256] f32

    const int R = in_sizes[1];          // 100,000
    const int total_f4 = R * 64;        // 6.4M 16B moves
    const int block = 256;
    // 8 f32x4 per thread: 6,400,000 / (256*8) = 3125 blocks, exact (no tail).
    int grid = (total_f4 + block * 8 - 1) / (block * 8);
    if (grid < 1) grid = 1;

    StructuredReadout_47287589929655_kernel<<<grid, block, 0, stream>>>(
        src, idx, dst, total_f4);
}

// Round 5
// 36.523 us; speedup vs baseline: 1.0154x; 1.0154x over previous
//
#include <hip/hip_runtime.h>

// StructuredReadout: out[r, :] = node_states[idx[r], :]
// node_states: [N=1e6, D=256] f32 (1 GiB), idx: [R=1e5] int, out: [R, 256] f32.
//
// Best-known config (round 3, 35.96 us = ~5.7 TB/s, ~90% achievable HBM):
// - One 64-lane wave moves one 1 KiB row (16 B per lane), fully coalesced.
// - 4-way independent unroll: 4 gather loads in flight per thread before any
//   store (VMEM MLP to cover ~900-cycle random HBM-miss latency).
// - 6250 blocks keeps TLP high (8-way/3125 blocks regressed: 37.1 us).
// - Non-temporal stores: output written once, never re-read.
// - Normal (cached) gather loads: distinct gathered rows ~95 MB < 256 MB L3,
//   so duplicate indices (~5%) hit L3; nt loads would forfeit that.

typedef float f32x4 __attribute__((ext_vector_type(4)));

__global__ __launch_bounds__(256) void StructuredReadout_47287589929655_kernel(
    const f32x4* __restrict__ src,    // node_states as [N, 64] f32x4
    const int* __restrict__ idx,      // readout indices [R]
    f32x4* __restrict__ dst,          // out as [R, 64] f32x4
    int total_f4)                     // R * 64
{
    const int S   = gridDim.x * blockDim.x;
    const int gid = blockIdx.x * blockDim.x + threadIdx.x;

    int g0 = gid, g1 = gid + S, g2 = gid + 2 * S, g3 = gid + 3 * S;

    if (g3 < total_f4) {
        // Fast path: 4 independent gathers issued before any store.
        long long r0 = idx[g0 >> 6], r1 = idx[g1 >> 6];
        long long r2 = idx[g2 >> 6], r3 = idx[g3 >> 6];
        f32x4 v0 = src[r0 * 64 + (g0 & 63)];
        f32x4 v1 = src[r1 * 64 + (g1 & 63)];
        f32x4 v2 = src[r2 * 64 + (g2 & 63)];
        f32x4 v3 = src[r3 * 64 + (g3 & 63)];
        __builtin_nontemporal_store(v0, &dst[g0]);
        __builtin_nontemporal_store(v1, &dst[g1]);
        __builtin_nontemporal_store(v2, &dst[g2]);
        __builtin_nontemporal_store(v3, &dst[g3]);
    } else {
        for (int g = g0; g < total_f4; g += S) {
            long long r = idx[g >> 6];
            f32x4 v = src[r * 64 + (g & 63)];
            __builtin_nontemporal_store(v, &dst[g]);
        }
    }
}

extern "C" void kernel_launch(void* const* d_in, const int* in_sizes, int n_in,
                              void* d_out, int out_size, void* d_ws, size_t ws_size,
                              hipStream_t stream) {
    const f32x4* src = (const f32x4*)d_in[0];     // node_states [1e6 * 256] f32
    const int*   idx = (const int*)d_in[1];       // readout_indices [1e5]
    f32x4*       dst = (f32x4*)d_out;             // [1e5 * 256] f32

    const int R = in_sizes[1];          // 100,000
    const int total_f4 = R * 64;        // 6.4M 16B moves
    const int block = 256;
    // 4 f32x4 per thread; grid covers total in one 4-deep stride pass.
    int grid = (total_f4 + block * 4 - 1) / (block * 4);   // 6250
    if (grid < 1) grid = 1;

    StructuredReadout_47287589929655_kernel<<<grid, block, 0, stream>>>(
        src, idx, dst, total_f4);
}